// Round 1
// baseline (124.071 us; speedup 1.0000x reference)
//
#include <hip/hip_runtime.h>

// SimpleMatcher: B=128, N=900 preds, T=300 targets.
// out = [pred_idx (B*T), valid (B*T), max_iou (B*T)] as float.
//
// R6 theory: R5 scan was LDS-throughput-bound, not VALU-bound. Inner loop
// issued 2 ds_reads/iter (b128 sp + b32 spa); at ~12+6 cyc/CU-pipe that's
// ~34us of LDS time vs ~13us VALU floor. Preds are wave-uniform -> move
// them to the SCALAR pipe: prep kernel pre-transforms preds to
// [B*N][8] floats (x0,y0,x1,y1,pa,pw,ph,0); scan reads them via block-
// uniform indices through __restrict__ const ptr -> s_load_dwordx8
// (scalar cache, concurrent with VALU). No LDS in the inner loop at all.
// Also: ew = max(px1,tx1)-min(px0,tx0) == (pw+tw)-wr (min+max=sum
// identity), cutting 28 -> 23 VALU/iter. Extra rounding <= ~2.5e-6,
// 8x inside MARGIN=2e-5; exact-rescan safety net unchanged.
// Fixed floor: harness's 256MiB 0xAA ws-poison (~41us) is in-window.

#define BB 128
#define NN 900
#define TT 300
#define TCHUNK 64      // targets per block (64 lanes)
#define TBLOCKS 5      // ceil(TT / TCHUNK)
#define NSPLIT 5       // n-splits across blocks
#define NPB 180        // preds per block  (NN / NSPLIT)
#define NPW 45         // preds per wave   (NPB / 4)
#define MARGIN 2e-5f

// Bit-exact GIoU in numpy's exact expression order.
__device__ __forceinline__ float giou_exact(float4 pb, float4 tb) {
#pragma clang fp contract(off)
    float px0 = pb.x - 0.5f * pb.z, py0 = pb.y - 0.5f * pb.w;
    float px1 = pb.x + 0.5f * pb.z, py1 = pb.y + 0.5f * pb.w;
    float tx0 = tb.x - 0.5f * tb.z, ty0 = tb.y - 0.5f * tb.w;
    float tx1 = tb.x + 0.5f * tb.z, ty1 = tb.y + 0.5f * tb.w;
    float pa = (px1 - px0) * (py1 - py0);
    float ta = (tx1 - tx0) * (ty1 - ty0);
    float w  = fmaxf(fminf(px1, tx1) - fmaxf(px0, tx0), 0.f);
    float h  = fmaxf(fminf(py1, ty1) - fmaxf(py0, ty0), 0.f);
    float inter = w * h;
    float uni   = pa + ta - inter;
    float iou   = inter / uni;            // correctly-rounded IEEE div
    float ew = fmaxf(fmaxf(px1, tx1) - fminf(px0, tx0), 0.f);
    float eh = fmaxf(fmaxf(py1, ty1) - fminf(py0, ty0), 0.f);
    float ea = ew * eh;
    return iou - (ea - uni) / ea;         // correctly-rounded IEEE div
}

// Pre-transform preds once: [B*N] -> 2x float4 {x0,y0,x1,y1},{pa,pw,ph,0}.
// Amortizes the cxcywh->xyxy transform across the 25 scan blocks per batch
// that previously each redid it, and feeds the scan's scalar-load path.
__global__ __launch_bounds__(256) void matcher_prep_kernel(
    const float4* __restrict__ pred,      // [B*N] cxcywh
    float4* __restrict__ pxy)             // [B*N][2]
{
    const int i = blockIdx.x * 256 + threadIdx.x;
    if (i >= BB * NN) return;
    const float4 pb = pred[i];
    float4 q;
    q.x = pb.x - 0.5f * pb.z;
    q.y = pb.y - 0.5f * pb.w;
    q.z = pb.x + 0.5f * pb.z;
    q.w = pb.y + 0.5f * pb.w;
    const float pw = q.z - q.x;
    const float ph = q.w - q.y;
    float4 c;
    c.x = pw * ph;                        // pa, bit-identical to R5's spa
    c.y = pw;
    c.z = ph;
    c.w = 0.f;
    pxy[2 * i]     = q;
    pxy[2 * i + 1] = c;
}

__global__ __launch_bounds__(256, 8) void matcher_scan_kernel(
    const float4* __restrict__ pxy,       // [B*N][2] pred xyxy + (pa,pw,ph)
    const float* __restrict__ tgt,        // [B,T,4] cxcywh
    float* __restrict__ pbest,            // [NSPLIT][B*T]
    float* __restrict__ psec,             // [NSPLIT][B*T]
    int*   __restrict__ pidx)             // [NSPLIT][B*T]
{
    __shared__ float rbv[256], rsv[256];  // cross-wave reduce only
    __shared__ int   riv[256];

    const int ns  = blockIdx.x % NSPLIT;
    const int tc  = (blockIdx.x / NSPLIT) % TBLOCKS;
    const int b   = blockIdx.x / (NSPLIT * TBLOCKS);
    const int tid = threadIdx.x;
    const int tl  = tid & 63;
    const int ng  = tid >> 6;
    const int t   = tc * TCHUNK + tl;

    float tx0 = 0.f, ty0 = 0.f, tx1 = 0.f, ty1 = 0.f;
    float ta = 0.f, tw = 0.f, th = 0.f;
    if (t < TT) {
        const float4 tb = ((const float4*)tgt)[b * TT + t];
        tx0 = tb.x - 0.5f * tb.z;
        ty0 = tb.y - 0.5f * tb.w;
        tx1 = tb.x + 0.5f * tb.z;
        ty1 = tb.y + 0.5f * tb.w;
        tw = tx1 - tx0;
        th = ty1 - ty0;
        ta = tw * th;                     // == reference area_t
    }

    // Block-uniform base -> all inner-loop pred reads are wave-uniform
    // with immediate offsets: compiler emits s_load_dwordx8 (scalar pipe).
    const int k0 = ng * NPW;
    const float4* pp = pxy + 2 * (b * NN + ns * NPB + k0);

    float best = -INFINITY, second = -INFINITY;
    int   bidxl = 0;                      // local k: inline-const cndmask
    #pragma unroll 5
    for (int k = 0; k < NPW; ++k) {
        const float4 q = pp[2 * k];       // (px0,py0,px1,py1) -> SGPRs
        const float4 c = pp[2 * k + 1];   // (pa,pw,ph,-)      -> SGPRs

        const float m1x = fminf(q.z, tx1);
        const float M0x = fmaxf(q.x, tx0);
        const float wr  = m1x - M0x;      // unclamped intersect width
        const float w   = fmaxf(wr, 0.f);
        const float m1y = fminf(q.w, ty1);
        const float M0y = fmaxf(q.y, ty0);
        const float hr  = m1y - M0y;
        const float h   = fmaxf(hr, 0.f);
        const float inter = w * h;
        const float uni   = (c.x + ta) - inter;

        // min+max=sum identity: ew = max(px1,tx1)-min(px0,tx0) = pw+tw-wr
        const float ew = (c.y + tw) - wr;
        const float eh = (c.z + th) - hr;
        const float ea = ew * eh;

        // g = inter/uni - (ea-uni)/ea == (inter*ea + uni*(uni-ea))/(uni*ea)
        const float num = fmaf(inter, ea, uni * (uni - ea));
        const float g   = num * __builtin_amdgcn_rcpf(uni * ea);

        second = __builtin_amdgcn_fmed3f(g, best, second);  // new 2nd-max
        if (g > best) bidxl = k;
        best = fmaxf(best, g);
    }
    int bidx = k0 + bidxl;

    rbv[tid] = best; rsv[tid] = second; riv[tid] = bidx;
    __syncthreads();

    if (ng == 0 && t < TT) {
        for (int s = 1; s < 4; ++s) {     // ascending wave = ascending n
            const float ob = rbv[s * 64 + tl];
            const float os = rsv[s * 64 + tl];
            const int   oi = riv[s * 64 + tl];
            second = fmaxf(fminf(best, ob), fmaxf(second, os));
            if (ob > best) { best = ob; bidx = oi; }
        }
        const int bt = b * TT + t;
        pbest[ns * BB * TT + bt] = best;
        psec [ns * BB * TT + bt] = second;
        pidx [ns * BB * TT + bt] = ns * NPB + bidx;   // global pred index
    }
}

__global__ __launch_bounds__(256) void matcher_finish_kernel(
    const float* __restrict__ pbest,
    const float* __restrict__ psec,
    const int*   __restrict__ pidx,
    const float* __restrict__ pred,
    const float* __restrict__ tgt,
    const unsigned char* __restrict__ mask,
    float* __restrict__ out)
{
    __shared__ int sflag[256];
    __shared__ int scount;

    const int tid = threadIdx.x;
    const int bt  = blockIdx.x * 256 + tid;   // grid covers exactly B*T
    if (tid == 0) scount = 0;
    __syncthreads();

    float best = -INFINITY, second = -INFINITY;
    int   bidx = 0;
    #pragma unroll
    for (int s = 0; s < NSPLIT; ++s) {        // ascending ns = ascending n
        const float ob = pbest[s * BB * TT + bt];
        const float os = psec [s * BB * TT + bt];
        const int   oi = pidx [s * BB * TT + bt];
        second = fmaxf(fminf(best, ob), fmaxf(second, os));
        if (ob > best) { best = ob; bidx = oi; }
    }

    if (best - second > MARGIN) {
        // approx argmax provably exact; recompute winner's GIoU bit-exactly
        const int b = bt / TT;
        const float4 pb = ((const float4*)pred)[b * NN + bidx];
        const float4 tb = ((const float4*)tgt)[bt];
        const float g = giou_exact(pb, tb);
        const bool valid = (mask[bt] != 0) && (g >= 0.5f);
        out[bt]               = (float)bidx;
        out[BB * TT + bt]     = valid ? 1.f : 0.f;
        out[2 * BB * TT + bt] = g;
    } else {
        const int pos = atomicAdd(&scount, 1);
        sflag[pos] = tid;
    }
    __syncthreads();

    // cooperative exact rescan of ambiguous targets: one wave per entry
    const int cnt  = scount;
    const int lane = tid & 63;
    const int ng   = tid >> 6;
    for (int f = ng; f < cnt; f += 4) {
        const int fbt = blockIdx.x * 256 + sflag[f];
        const int b   = fbt / TT;
        const float4 tb = ((const float4*)tgt)[fbt];

        float bestx = -INFINITY;
        int   bix   = NN;
        for (int n = lane; n < NN; n += 64) {   // ascending n per lane
            const float4 pb = ((const float4*)pred)[b * NN + n];
            const float g = giou_exact(pb, tb);
            if (g > bestx) { bestx = g; bix = n; }
        }
        // cross-lane reduce: max g, lowest n on bit-ties (numpy first-occ.)
        for (int off = 32; off >= 1; off >>= 1) {
            const float ob = __shfl_xor(bestx, off);
            const int   oi = __shfl_xor(bix, off);
            if (ob > bestx || (ob == bestx && oi < bix)) { bestx = ob; bix = oi; }
        }
        if (lane == 0) {
            const bool valid = (mask[fbt] != 0) && (bestx >= 0.5f);
            out[fbt]               = (float)bix;
            out[BB * TT + fbt]     = valid ? 1.f : 0.f;
            out[2 * BB * TT + fbt] = bestx;
        }
    }
}

extern "C" void kernel_launch(void* const* d_in, const int* in_sizes, int n_in,
                              void* d_out, int out_size, void* d_ws, size_t ws_size,
                              hipStream_t stream) {
    const float* pred = (const float*)d_in[0];
    const float* tgt  = (const float*)d_in[1];
    const unsigned char* mask = (const unsigned char*)d_in[2];
    float* out = (float*)d_out;

    const size_t seg = (size_t)NSPLIT * BB * TT * 4;   // 768 KB per array
    char* ws = (char*)d_ws;
    float*  pbest = (float*)ws;
    float*  psec  = (float*)(ws + seg);
    int*    pidx  = (int*)  (ws + 2 * seg);
    float4* pxy   = (float4*)(ws + 3 * seg);           // [B*N][2] = 3.7 MB

    matcher_prep_kernel<<<dim3((BB * NN + 255) / 256), dim3(256), 0, stream>>>(
        (const float4*)pred, pxy);
    matcher_scan_kernel<<<dim3(BB * TBLOCKS * NSPLIT), dim3(256), 0, stream>>>(
        pxy, tgt, pbest, psec, pidx);
    matcher_finish_kernel<<<dim3(BB * TT / 256), dim3(256), 0, stream>>>(
        pbest, psec, pidx, pred, tgt, mask, out);
}

// Round 2
// 100.147 us; speedup vs baseline: 1.2389x; 1.2389x over previous
//
#include <hip/hip_runtime.h>

// SimpleMatcher: B=128, N=900 preds, T=300 targets.
// out = [pred_idx (B*T), valid (B*T), max_iou (B*T)] as float.
//
// R7: R6's scalar-load plan failed because LLVM divergence analysis can't
// prove ng=tid>>6 is wave-uniform (scan SGPR_Count=32 => no s_load; loads
// became per-lane global_load_dwordx4 broadcasts, VALUBusy 47%, 59.5us).
// Fix: __builtin_amdgcn_readfirstlane on the wave-uniform element offset
// => base ptr + SGPR offset => backend selects s_load_dwordx4/x8 (scalar
// cache, concurrent with VALU; loads are __restrict__ const, unclobbered).
// Inner loop: 0 VMEM, 0 LDS, ~27 VALU/iter -> ~12.6us VALU floor.
// Numerics identical to R6 (passed, absmax 1.0): min+max=sum identity for
// enclosing box, rcp-based GIoU with MARGIN 2e-5 + exact rescan net.
// Fixed floor: harness's 256MiB 0xAA ws-poison fill (~41us) is in-window.

#define BB 128
#define NN 900
#define TT 300
#define TCHUNK 64      // targets per block (64 lanes)
#define TBLOCKS 5      // ceil(TT / TCHUNK)
#define NSPLIT 5       // n-splits across blocks
#define NPB 180        // preds per block  (NN / NSPLIT)
#define NPW 45         // preds per wave   (NPB / 4)
#define MARGIN 2e-5f

// Bit-exact GIoU in numpy's exact expression order.
__device__ __forceinline__ float giou_exact(float4 pb, float4 tb) {
#pragma clang fp contract(off)
    float px0 = pb.x - 0.5f * pb.z, py0 = pb.y - 0.5f * pb.w;
    float px1 = pb.x + 0.5f * pb.z, py1 = pb.y + 0.5f * pb.w;
    float tx0 = tb.x - 0.5f * tb.z, ty0 = tb.y - 0.5f * tb.w;
    float tx1 = tb.x + 0.5f * tb.z, ty1 = tb.y + 0.5f * tb.w;
    float pa = (px1 - px0) * (py1 - py0);
    float ta = (tx1 - tx0) * (ty1 - ty0);
    float w  = fmaxf(fminf(px1, tx1) - fmaxf(px0, tx0), 0.f);
    float h  = fmaxf(fminf(py1, ty1) - fmaxf(py0, ty0), 0.f);
    float inter = w * h;
    float uni   = pa + ta - inter;
    float iou   = inter / uni;            // correctly-rounded IEEE div
    float ew = fmaxf(fmaxf(px1, tx1) - fminf(px0, tx0), 0.f);
    float eh = fmaxf(fmaxf(py1, ty1) - fminf(py0, ty0), 0.f);
    float ea = ew * eh;
    return iou - (ea - uni) / ea;         // correctly-rounded IEEE div
}

// Pre-transform preds once: [B*N] -> 2x float4 {x0,y0,x1,y1},{pa,pw,ph,0}.
__global__ __launch_bounds__(256) void matcher_prep_kernel(
    const float4* __restrict__ pred,      // [B*N] cxcywh
    float4* __restrict__ pxy)             // [B*N][2]
{
    const int i = blockIdx.x * 256 + threadIdx.x;
    if (i >= BB * NN) return;
    const float4 pb = pred[i];
    float4 q;
    q.x = pb.x - 0.5f * pb.z;
    q.y = pb.y - 0.5f * pb.w;
    q.z = pb.x + 0.5f * pb.z;
    q.w = pb.y + 0.5f * pb.w;
    const float pw = q.z - q.x;
    const float ph = q.w - q.y;
    float4 c;
    c.x = pw * ph;                        // pa, bit-identical to R5's spa
    c.y = pw;
    c.z = ph;
    c.w = 0.f;
    pxy[2 * i]     = q;
    pxy[2 * i + 1] = c;
}

__global__ __launch_bounds__(256, 8) void matcher_scan_kernel(
    const float4* __restrict__ pxy,       // [B*N][2] pred xyxy + (pa,pw,ph)
    const float* __restrict__ tgt,        // [B,T,4] cxcywh
    float* __restrict__ pbest,            // [NSPLIT][B*T]
    float* __restrict__ psec,             // [NSPLIT][B*T]
    int*   __restrict__ pidx)             // [NSPLIT][B*T]
{
    __shared__ float rbv[256], rsv[256];  // cross-wave reduce only
    __shared__ int   riv[256];

    const int ns  = blockIdx.x % NSPLIT;
    const int tc  = (blockIdx.x / NSPLIT) % TBLOCKS;
    const int b   = blockIdx.x / (NSPLIT * TBLOCKS);
    const int tid = threadIdx.x;
    const int tl  = tid & 63;
    const int ng  = tid >> 6;
    const int t   = tc * TCHUNK + tl;

    float tx0 = 0.f, ty0 = 0.f, tx1 = 0.f, ty1 = 0.f;
    float ta = 0.f, tw = 0.f, th = 0.f;
    if (t < TT) {
        const float4 tb = ((const float4*)tgt)[b * TT + t];
        tx0 = tb.x - 0.5f * tb.z;
        ty0 = tb.y - 0.5f * tb.w;
        tx1 = tb.x + 0.5f * tb.z;
        ty1 = tb.y + 0.5f * tb.w;
        tw = tx1 - tx0;
        th = ty1 - ty0;
        ta = tw * th;                     // == reference area_t
    }

    // ng*NPW is wave-uniform but divergence analysis can't prove it:
    // readfirstlane forces the offset into an SGPR, making every pred
    // load in the loop a uniform address => s_load_dwordx4 (scalar pipe).
    const int k0 = ng * NPW;
    const int kbase =
        __builtin_amdgcn_readfirstlane(2 * (b * NN + ns * NPB + k0));
    const float4* pp = pxy + kbase;

    float best = -INFINITY, second = -INFINITY;
    int   bidxl = 0;                      // local k: inline-const cndmask
    #pragma unroll 9
    for (int k = 0; k < NPW; ++k) {
        const float4 q = pp[2 * k];       // (px0,py0,px1,py1) -> SGPRs
        const float4 c = pp[2 * k + 1];   // (pa,pw,ph,-)      -> SGPRs

        const float m1x = fminf(q.z, tx1);
        const float M0x = fmaxf(q.x, tx0);
        const float wr  = m1x - M0x;      // unclamped intersect width
        const float w   = fmaxf(wr, 0.f);
        const float m1y = fminf(q.w, ty1);
        const float M0y = fmaxf(q.y, ty0);
        const float hr  = m1y - M0y;
        const float h   = fmaxf(hr, 0.f);
        const float inter = w * h;
        const float uni   = (c.x + ta) - inter;

        // min+max=sum identity: ew = max(px1,tx1)-min(px0,tx0) = pw+tw-wr
        const float ew = (c.y + tw) - wr;
        const float eh = (c.z + th) - hr;
        const float ea = ew * eh;

        // g = inter/uni - (ea-uni)/ea == (inter*ea + uni*(uni-ea))/(uni*ea)
        const float num = fmaf(inter, ea, uni * (uni - ea));
        const float g   = num * __builtin_amdgcn_rcpf(uni * ea);

        second = __builtin_amdgcn_fmed3f(g, best, second);  // new 2nd-max
        if (g > best) bidxl = k;
        best = fmaxf(best, g);
    }
    int bidx = k0 + bidxl;

    rbv[tid] = best; rsv[tid] = second; riv[tid] = bidx;
    __syncthreads();

    if (ng == 0 && t < TT) {
        for (int s = 1; s < 4; ++s) {     // ascending wave = ascending n
            const float ob = rbv[s * 64 + tl];
            const float os = rsv[s * 64 + tl];
            const int   oi = riv[s * 64 + tl];
            second = fmaxf(fminf(best, ob), fmaxf(second, os));
            if (ob > best) { best = ob; bidx = oi; }
        }
        const int bt = b * TT + t;
        pbest[ns * BB * TT + bt] = best;
        psec [ns * BB * TT + bt] = second;
        pidx [ns * BB * TT + bt] = ns * NPB + bidx;   // global pred index
    }
}

__global__ __launch_bounds__(256) void matcher_finish_kernel(
    const float* __restrict__ pbest,
    const float* __restrict__ psec,
    const int*   __restrict__ pidx,
    const float* __restrict__ pred,
    const float* __restrict__ tgt,
    const unsigned char* __restrict__ mask,
    float* __restrict__ out)
{
    __shared__ int sflag[256];
    __shared__ int scount;

    const int tid = threadIdx.x;
    const int bt  = blockIdx.x * 256 + tid;   // grid covers exactly B*T
    if (tid == 0) scount = 0;
    __syncthreads();

    float best = -INFINITY, second = -INFINITY;
    int   bidx = 0;
    #pragma unroll
    for (int s = 0; s < NSPLIT; ++s) {        // ascending ns = ascending n
        const float ob = pbest[s * BB * TT + bt];
        const float os = psec [s * BB * TT + bt];
        const int   oi = pidx [s * BB * TT + bt];
        second = fmaxf(fminf(best, ob), fmaxf(second, os));
        if (ob > best) { best = ob; bidx = oi; }
    }

    if (best - second > MARGIN) {
        // approx argmax provably exact; recompute winner's GIoU bit-exactly
        const int b = bt / TT;
        const float4 pb = ((const float4*)pred)[b * NN + bidx];
        const float4 tb = ((const float4*)tgt)[bt];
        const float g = giou_exact(pb, tb);
        const bool valid = (mask[bt] != 0) && (g >= 0.5f);
        out[bt]               = (float)bidx;
        out[BB * TT + bt]     = valid ? 1.f : 0.f;
        out[2 * BB * TT + bt] = g;
    } else {
        const int pos = atomicAdd(&scount, 1);
        sflag[pos] = tid;
    }
    __syncthreads();

    // cooperative exact rescan of ambiguous targets: one wave per entry
    const int cnt  = scount;
    const int lane = tid & 63;
    const int ng   = tid >> 6;
    for (int f = ng; f < cnt; f += 4) {
        const int fbt = blockIdx.x * 256 + sflag[f];
        const int b   = fbt / TT;
        const float4 tb = ((const float4*)tgt)[fbt];

        float bestx = -INFINITY;
        int   bix   = NN;
        for (int n = lane; n < NN; n += 64) {   // ascending n per lane
            const float4 pb = ((const float4*)pred)[b * NN + n];
            const float g = giou_exact(pb, tb);
            if (g > bestx) { bestx = g; bix = n; }
        }
        // cross-lane reduce: max g, lowest n on bit-ties (numpy first-occ.)
        for (int off = 32; off >= 1; off >>= 1) {
            const float ob = __shfl_xor(bestx, off);
            const int   oi = __shfl_xor(bix, off);
            if (ob > bestx || (ob == bestx && oi < bix)) { bestx = ob; bix = oi; }
        }
        if (lane == 0) {
            const bool valid = (mask[fbt] != 0) && (bestx >= 0.5f);
            out[fbt]               = (float)bix;
            out[BB * TT + fbt]     = valid ? 1.f : 0.f;
            out[2 * BB * TT + fbt] = bestx;
        }
    }
}

extern "C" void kernel_launch(void* const* d_in, const int* in_sizes, int n_in,
                              void* d_out, int out_size, void* d_ws, size_t ws_size,
                              hipStream_t stream) {
    const float* pred = (const float*)d_in[0];
    const float* tgt  = (const float*)d_in[1];
    const unsigned char* mask = (const unsigned char*)d_in[2];
    float* out = (float*)d_out;

    const size_t seg = (size_t)NSPLIT * BB * TT * 4;   // 768 KB per array
    char* ws = (char*)d_ws;
    float*  pbest = (float*)ws;
    float*  psec  = (float*)(ws + seg);
    int*    pidx  = (int*)  (ws + 2 * seg);
    float4* pxy   = (float4*)(ws + 3 * seg);           // [B*N][2] = 3.7 MB

    matcher_prep_kernel<<<dim3((BB * NN + 255) / 256), dim3(256), 0, stream>>>(
        (const float4*)pred, pxy);
    matcher_scan_kernel<<<dim3(BB * TBLOCKS * NSPLIT), dim3(256), 0, stream>>>(
        pxy, tgt, pbest, psec, pidx);
    matcher_finish_kernel<<<dim3(BB * TT / 256), dim3(256), 0, stream>>>(
        pbest, psec, pidx, pred, tgt, mask, out);
}

// Round 3
// 96.061 us; speedup vs baseline: 1.2916x; 1.0425x over previous
//
#include <hip/hip_runtime.h>

// SimpleMatcher: B=128, N=900 preds, T=300 targets.
// out = [pred_idx (B*T), valid (B*T), max_iou (B*T)] as float.
//
// R8: abandon the scalar-load gamble (R6 failed outright: SGPR=32, VMEM
// broadcast loads, 59.5us; R7's readfirstlane improved to ~35us but is
// unverifiable and confounded with unroll). Root model from R6 counters:
// VALU-busy ~28us and pred-fetch are CO-bottlenecks. Structural fix that
// is robust to fetch mechanism: 2 TARGETS PER LANE -> each LDS pred
// broadcast amortized over 2 GIoUs, wave count halves (LDS-pipe cyc/CU
// halve), VALU becomes the single dominant pipe (~13.5us floor).
// Partition: per (b,ns): 2 dual blocks (128 contiguous targets, lanes own
// t and t+64) + 1 single block (targets 256..299) -> slot waste 6.7%.
// Back to R5's LDS staging (known: 0 bank conflicts, broadcast reads).
// Numerics unchanged vs R5/R7 (passed, absmax 1.0): min+max=sum identity,
// rcp-based GIoU, MARGIN 2e-5, exact-rescan + bit-exact winner recompute.
// Fixed floor: harness's 256MiB 0xAA ws-poison fill (~42us) in-window.

#define BB 128
#define NN 900
#define TT 300
#define NSPLIT 5       // n-splits across blocks
#define NPB 180        // preds per block  (NN / NSPLIT)
#define NPW 45         // preds per wave   (NPB / 4)
#define MARGIN 2e-5f

// Bit-exact GIoU in numpy's exact expression order.
__device__ __forceinline__ float giou_exact(float4 pb, float4 tb) {
#pragma clang fp contract(off)
    float px0 = pb.x - 0.5f * pb.z, py0 = pb.y - 0.5f * pb.w;
    float px1 = pb.x + 0.5f * pb.z, py1 = pb.y + 0.5f * pb.w;
    float tx0 = tb.x - 0.5f * tb.z, ty0 = tb.y - 0.5f * tb.w;
    float tx1 = tb.x + 0.5f * tb.z, ty1 = tb.y + 0.5f * tb.w;
    float pa = (px1 - px0) * (py1 - py0);
    float ta = (tx1 - tx0) * (ty1 - ty0);
    float w  = fmaxf(fminf(px1, tx1) - fmaxf(px0, tx0), 0.f);
    float h  = fmaxf(fminf(py1, ty1) - fmaxf(py0, ty0), 0.f);
    float inter = w * h;
    float uni   = pa + ta - inter;
    float iou   = inter / uni;            // correctly-rounded IEEE div
    float ew = fmaxf(fmaxf(px1, tx1) - fminf(px0, tx0), 0.f);
    float eh = fmaxf(fmaxf(py1, ty1) - fminf(py0, ty0), 0.f);
    float ea = ew * eh;
    return iou - (ea - uni) / ea;         // correctly-rounded IEEE div
}

// One GIoU step against the LDS-broadcast pred (q,c), tracking top-2.
__device__ __forceinline__ void giou_step(
    const float4 q, const float4 c,
    const float tx0, const float ty0, const float tx1, const float ty1,
    const float tw, const float th, const float ta, const int k,
    float& best, float& second, int& bidxl)
{
    const float m1x = fminf(q.z, tx1);
    const float M0x = fmaxf(q.x, tx0);
    const float wr  = m1x - M0x;          // unclamped intersect width
    const float w   = fmaxf(wr, 0.f);
    const float m1y = fminf(q.w, ty1);
    const float M0y = fmaxf(q.y, ty0);
    const float hr  = m1y - M0y;
    const float h   = fmaxf(hr, 0.f);
    const float inter = w * h;
    const float uni   = (c.x + ta) - inter;
    // min+max=sum identity: ew = max(px1,tx1)-min(px0,tx0) = pw+tw-wr
    const float ew = (c.y + tw) - wr;
    const float eh = (c.z + th) - hr;
    const float ea = ew * eh;
    // g = inter/uni - (ea-uni)/ea == (inter*ea + uni*(uni-ea))/(uni*ea)
    const float num = fmaf(inter, ea, uni * (uni - ea));
    const float g   = num * __builtin_amdgcn_rcpf(uni * ea);
    second = __builtin_amdgcn_fmed3f(g, best, second);  // new 2nd-max
    if (g > best) bidxl = k;
    best = fmaxf(best, g);
}

__device__ __forceinline__ void load_target(
    const float4* __restrict__ tgt, const int idx,
    float& tx0, float& ty0, float& tx1, float& ty1,
    float& tw, float& th, float& ta)
{
    const float4 tb = tgt[idx];
    tx0 = tb.x - 0.5f * tb.z;
    ty0 = tb.y - 0.5f * tb.w;
    tx1 = tb.x + 0.5f * tb.z;
    ty1 = tb.y + 0.5f * tb.w;
    tw = tx1 - tx0;
    th = ty1 - ty0;
    ta = tw * th;                         // == reference area_t
}

// Grid: BB * 3 * NSPLIT. tc=0,1: dual blocks (targets tc*128 .. +127,
// lane owns t and t+64). tc=2: single block (targets 256..299).
__global__ __launch_bounds__(256, 8) void matcher_scan_kernel(
    const float4* __restrict__ pred,      // [B*N] cxcywh
    const float4* __restrict__ tgt,       // [B*T] cxcywh
    float* __restrict__ pbest,            // [NSPLIT][B*T]
    float* __restrict__ psec,             // [NSPLIT][B*T]
    int*   __restrict__ pidx)             // [NSPLIT][B*T]
{
    __shared__ float4 sq[NPB];            // pred xyxy
    __shared__ float4 scc[NPB];           // pred (pa,pw,ph,0)
    __shared__ float rb1[256], rs1[256], rb2[256], rs2[256];
    __shared__ int   ri1[256], ri2[256];

    const int ns  = blockIdx.x % NSPLIT;
    const int tc  = (blockIdx.x / NSPLIT) % 3;
    const int b   = blockIdx.x / (NSPLIT * 3);
    const int tid = threadIdx.x;
    const int tl  = tid & 63;
    const int ng  = tid >> 6;

    if (tid < NPB) {
        const float4 pb = pred[b * NN + ns * NPB + tid];
        float4 q;
        q.x = pb.x - 0.5f * pb.z;
        q.y = pb.y - 0.5f * pb.w;
        q.z = pb.x + 0.5f * pb.z;
        q.w = pb.y + 0.5f * pb.w;
        const float pw = q.z - q.x;
        const float ph = q.w - q.y;
        sq[tid]  = q;
        scc[tid] = make_float4(pw * ph, pw, ph, 0.f);
    }
    __syncthreads();

    const int k0 = ng * NPW;

    if (tc < 2) {
        // ---- dual path: both targets always valid (max index 255) ----
        const int t1 = tc * 128 + tl;
        const int t2 = t1 + 64;
        float ax0, ay0, ax1, ay1, aw, ah, aa;
        float bx0, by0, bx1, by1, bw, bh, ba;
        load_target(tgt, b * TT + t1, ax0, ay0, ax1, ay1, aw, ah, aa);
        load_target(tgt, b * TT + t2, bx0, by0, bx1, by1, bw, bh, ba);

        float best1 = -INFINITY, sec1 = -INFINITY;
        float best2 = -INFINITY, sec2 = -INFINITY;
        int   i1 = 0, i2 = 0;
        #pragma unroll 9
        for (int k = 0; k < NPW; ++k) {
            const float4 q = sq[k0 + k];  // wave-uniform -> LDS broadcast
            const float4 c = scc[k0 + k];
            giou_step(q, c, ax0, ay0, ax1, ay1, aw, ah, aa, k, best1, sec1, i1);
            giou_step(q, c, bx0, by0, bx1, by1, bw, bh, ba, k, best2, sec2, i2);
        }
        int bi1 = k0 + i1, bi2 = k0 + i2;

        rb1[tid] = best1; rs1[tid] = sec1; ri1[tid] = bi1;
        rb2[tid] = best2; rs2[tid] = sec2; ri2[tid] = bi2;
        __syncthreads();

        if (ng == 0) {
            for (int s = 1; s < 4; ++s) { // ascending wave = ascending n
                const float ob1 = rb1[s * 64 + tl];
                const float os1 = rs1[s * 64 + tl];
                const int   oi1 = ri1[s * 64 + tl];
                sec1 = fmaxf(fminf(best1, ob1), fmaxf(sec1, os1));
                if (ob1 > best1) { best1 = ob1; bi1 = oi1; }
                const float ob2 = rb2[s * 64 + tl];
                const float os2 = rs2[s * 64 + tl];
                const int   oi2 = ri2[s * 64 + tl];
                sec2 = fmaxf(fminf(best2, ob2), fmaxf(sec2, os2));
                if (ob2 > best2) { best2 = ob2; bi2 = oi2; }
            }
            const int bt1 = b * TT + t1;
            const int bt2 = b * TT + t2;
            pbest[ns * BB * TT + bt1] = best1;
            psec [ns * BB * TT + bt1] = sec1;
            pidx [ns * BB * TT + bt1] = ns * NPB + bi1;
            pbest[ns * BB * TT + bt2] = best2;
            psec [ns * BB * TT + bt2] = sec2;
            pidx [ns * BB * TT + bt2] = ns * NPB + bi2;
        }
    } else {
        // ---- single path: remainder targets 256..299 ----
        const int t = 256 + tl;
        float ax0 = 0.f, ay0 = 0.f, ax1 = 0.f, ay1 = 0.f;
        float aw = 0.f, ah = 0.f, aa = 0.f;
        if (t < TT)
            load_target(tgt, b * TT + t, ax0, ay0, ax1, ay1, aw, ah, aa);

        float best = -INFINITY, second = -INFINITY;
        int   bidxl = 0;
        #pragma unroll 9
        for (int k = 0; k < NPW; ++k) {
            const float4 q = sq[k0 + k];
            const float4 c = scc[k0 + k];
            giou_step(q, c, ax0, ay0, ax1, ay1, aw, ah, aa, k, best, second, bidxl);
        }
        int bidx = k0 + bidxl;

        rb1[tid] = best; rs1[tid] = second; ri1[tid] = bidx;
        __syncthreads();

        if (ng == 0 && t < TT) {
            for (int s = 1; s < 4; ++s) { // ascending wave = ascending n
                const float ob = rb1[s * 64 + tl];
                const float os = rs1[s * 64 + tl];
                const int   oi = ri1[s * 64 + tl];
                second = fmaxf(fminf(best, ob), fmaxf(second, os));
                if (ob > best) { best = ob; bidx = oi; }
            }
            const int bt = b * TT + t;
            pbest[ns * BB * TT + bt] = best;
            psec [ns * BB * TT + bt] = second;
            pidx [ns * BB * TT + bt] = ns * NPB + bidx;
        }
    }
}

__global__ __launch_bounds__(256) void matcher_finish_kernel(
    const float* __restrict__ pbest,
    const float* __restrict__ psec,
    const int*   __restrict__ pidx,
    const float* __restrict__ pred,
    const float* __restrict__ tgt,
    const unsigned char* __restrict__ mask,
    float* __restrict__ out)
{
    __shared__ int sflag[256];
    __shared__ int scount;

    const int tid = threadIdx.x;
    const int bt  = blockIdx.x * 256 + tid;   // grid covers exactly B*T
    if (tid == 0) scount = 0;
    __syncthreads();

    float best = -INFINITY, second = -INFINITY;
    int   bidx = 0;
    #pragma unroll
    for (int s = 0; s < NSPLIT; ++s) {        // ascending ns = ascending n
        const float ob = pbest[s * BB * TT + bt];
        const float os = psec [s * BB * TT + bt];
        const int   oi = pidx [s * BB * TT + bt];
        second = fmaxf(fminf(best, ob), fmaxf(second, os));
        if (ob > best) { best = ob; bidx = oi; }
    }

    if (best - second > MARGIN) {
        // approx argmax provably exact; recompute winner's GIoU bit-exactly
        const int b = bt / TT;
        const float4 pb = ((const float4*)pred)[b * NN + bidx];
        const float4 tb = ((const float4*)tgt)[bt];
        const float g = giou_exact(pb, tb);
        const bool valid = (mask[bt] != 0) && (g >= 0.5f);
        out[bt]               = (float)bidx;
        out[BB * TT + bt]     = valid ? 1.f : 0.f;
        out[2 * BB * TT + bt] = g;
    } else {
        const int pos = atomicAdd(&scount, 1);
        sflag[pos] = tid;
    }
    __syncthreads();

    // cooperative exact rescan of ambiguous targets: one wave per entry
    const int cnt  = scount;
    const int lane = tid & 63;
    const int ng   = tid >> 6;
    for (int f = ng; f < cnt; f += 4) {
        const int fbt = blockIdx.x * 256 + sflag[f];
        const int b   = fbt / TT;
        const float4 tb = ((const float4*)tgt)[fbt];

        float bestx = -INFINITY;
        int   bix   = NN;
        for (int n = lane; n < NN; n += 64) {   // ascending n per lane
            const float4 pb = ((const float4*)pred)[b * NN + n];
            const float g = giou_exact(pb, tb);
            if (g > bestx) { bestx = g; bix = n; }
        }
        // cross-lane reduce: max g, lowest n on bit-ties (numpy first-occ.)
        for (int off = 32; off >= 1; off >>= 1) {
            const float ob = __shfl_xor(bestx, off);
            const int   oi = __shfl_xor(bix, off);
            if (ob > bestx || (ob == bestx && oi < bix)) { bestx = ob; bix = oi; }
        }
        if (lane == 0) {
            const bool valid = (mask[fbt] != 0) && (bestx >= 0.5f);
            out[fbt]               = (float)bix;
            out[BB * TT + fbt]     = valid ? 1.f : 0.f;
            out[2 * BB * TT + fbt] = bestx;
        }
    }
}

extern "C" void kernel_launch(void* const* d_in, const int* in_sizes, int n_in,
                              void* d_out, int out_size, void* d_ws, size_t ws_size,
                              hipStream_t stream) {
    const float* pred = (const float*)d_in[0];
    const float* tgt  = (const float*)d_in[1];
    const unsigned char* mask = (const unsigned char*)d_in[2];
    float* out = (float*)d_out;

    const size_t seg = (size_t)NSPLIT * BB * TT * 4;   // 768 KB per array
    char* ws = (char*)d_ws;
    float* pbest = (float*)ws;
    float* psec  = (float*)(ws + seg);
    int*   pidx  = (int*)  (ws + 2 * seg);             // total ~2.3 MB

    matcher_scan_kernel<<<dim3(BB * 3 * NSPLIT), dim3(256), 0, stream>>>(
        (const float4*)pred, (const float4*)tgt, pbest, psec, pidx);
    matcher_finish_kernel<<<dim3(BB * TT / 256), dim3(256), 0, stream>>>(
        pbest, psec, pidx, pred, tgt, mask, out);
}

// Round 4
// 94.825 us; speedup vs baseline: 1.3084x; 1.0130x over previous
//
#include <hip/hip_runtime.h>

// SimpleMatcher: B=128, N=900 preds, T=300 targets.
// out = [pred_idx (B*T), valid (B*T), max_iou (B*T)] as float.
//
// R9: the real scan bottleneck was REGISTER STARVATION, not LDS/VALU
// throughput. Evidence: R6 showed VGPR_Count=32 (forced by
// __launch_bounds__(256,8)); R8 halved waves AND LDS traffic yet got
// slightly WORSE (scan ~32->35us across R5/R7/R8, VALUBusy ~50%).
// At 32 VGPRs the unrolled loop can't keep ds_reads in flight -> every
// iteration group exposes ~120cyc LDS latency (load, lgkmcnt(0), use).
// Fix: __launch_bounds__(256,4) -> 64-VGPR budget, 2-3 iters of loads
// pipelined; 4 waves/SIMD with ILP > 8 stall-bound waves.
// Also: drop scc LDS array; derive pw,ph,pa from q in-loop (3 VALU,
// shared across the 2 targets, bit-identical) -> 1 ds_read_b128/iter,
// less staging, fewer live regs. Keep R8 dual-target partition.
// Numerics unchanged (R5..R8 all passed, absmax 1.0): min+max=sum
// identity, rcp GIoU, MARGIN 2e-5, exact rescan + bit-exact winner.
// Fixed floor: harness 256MiB ws-poison fill (~40us) + ~21us finish/gaps.

#define BB 128
#define NN 900
#define TT 300
#define NSPLIT 5       // n-splits across blocks
#define NPB 180        // preds per block  (NN / NSPLIT)
#define NPW 45         // preds per wave   (NPB / 4)
#define MARGIN 2e-5f

// Bit-exact GIoU in numpy's exact expression order.
__device__ __forceinline__ float giou_exact(float4 pb, float4 tb) {
#pragma clang fp contract(off)
    float px0 = pb.x - 0.5f * pb.z, py0 = pb.y - 0.5f * pb.w;
    float px1 = pb.x + 0.5f * pb.z, py1 = pb.y + 0.5f * pb.w;
    float tx0 = tb.x - 0.5f * tb.z, ty0 = tb.y - 0.5f * tb.w;
    float tx1 = tb.x + 0.5f * tb.z, ty1 = tb.y + 0.5f * tb.w;
    float pa = (px1 - px0) * (py1 - py0);
    float ta = (tx1 - tx0) * (ty1 - ty0);
    float w  = fmaxf(fminf(px1, tx1) - fmaxf(px0, tx0), 0.f);
    float h  = fmaxf(fminf(py1, ty1) - fmaxf(py0, ty0), 0.f);
    float inter = w * h;
    float uni   = pa + ta - inter;
    float iou   = inter / uni;            // correctly-rounded IEEE div
    float ew = fmaxf(fmaxf(px1, tx1) - fminf(px0, tx0), 0.f);
    float eh = fmaxf(fmaxf(py1, ty1) - fminf(py0, ty0), 0.f);
    float ea = ew * eh;
    return iou - (ea - uni) / ea;         // correctly-rounded IEEE div
}

// One GIoU step vs the LDS-broadcast pred (q + derived pa,pw,ph), top-2.
__device__ __forceinline__ void giou_step(
    const float4 q, const float pa, const float pw, const float ph,
    const float tx0, const float ty0, const float tx1, const float ty1,
    const float tw, const float th, const float ta, const int k,
    float& best, float& second, int& bidxl)
{
    const float m1x = fminf(q.z, tx1);
    const float M0x = fmaxf(q.x, tx0);
    const float wr  = m1x - M0x;          // unclamped intersect width
    const float w   = fmaxf(wr, 0.f);
    const float m1y = fminf(q.w, ty1);
    const float M0y = fmaxf(q.y, ty0);
    const float hr  = m1y - M0y;
    const float h   = fmaxf(hr, 0.f);
    const float inter = w * h;
    const float uni   = (pa + ta) - inter;
    // min+max=sum identity: ew = max(px1,tx1)-min(px0,tx0) = pw+tw-wr
    const float ew = (pw + tw) - wr;
    const float eh = (ph + th) - hr;
    const float ea = ew * eh;
    // g = inter/uni - (ea-uni)/ea == (inter*ea + uni*(uni-ea))/(uni*ea)
    const float num = fmaf(inter, ea, uni * (uni - ea));
    const float g   = num * __builtin_amdgcn_rcpf(uni * ea);
    second = __builtin_amdgcn_fmed3f(g, best, second);  // new 2nd-max
    if (g > best) bidxl = k;
    best = fmaxf(best, g);
}

__device__ __forceinline__ void load_target(
    const float4* __restrict__ tgt, const int idx,
    float& tx0, float& ty0, float& tx1, float& ty1,
    float& tw, float& th, float& ta)
{
    const float4 tb = tgt[idx];
    tx0 = tb.x - 0.5f * tb.z;
    ty0 = tb.y - 0.5f * tb.w;
    tx1 = tb.x + 0.5f * tb.z;
    ty1 = tb.y + 0.5f * tb.w;
    tw = tx1 - tx0;
    th = ty1 - ty0;
    ta = tw * th;                         // == reference area_t
}

// Grid: BB * 3 * NSPLIT. tc=0,1: dual blocks (targets tc*128 .. +127,
// lane owns t and t+64). tc=2: single block (targets 256..299).
__global__ __launch_bounds__(256, 4) void matcher_scan_kernel(
    const float4* __restrict__ pred,      // [B*N] cxcywh
    const float4* __restrict__ tgt,       // [B*T] cxcywh
    float* __restrict__ pbest,            // [NSPLIT][B*T]
    float* __restrict__ psec,             // [NSPLIT][B*T]
    int*   __restrict__ pidx)             // [NSPLIT][B*T]
{
    __shared__ float4 sq[NPB];            // pred xyxy (only LDS pred data)
    __shared__ float rb1[256], rs1[256], rb2[256], rs2[256];
    __shared__ int   ri1[256], ri2[256];

    const int ns  = blockIdx.x % NSPLIT;
    const int tc  = (blockIdx.x / NSPLIT) % 3;
    const int b   = blockIdx.x / (NSPLIT * 3);
    const int tid = threadIdx.x;
    const int tl  = tid & 63;
    const int ng  = tid >> 6;

    if (tid < NPB) {
        const float4 pb = pred[b * NN + ns * NPB + tid];
        float4 q;
        q.x = pb.x - 0.5f * pb.z;
        q.y = pb.y - 0.5f * pb.w;
        q.z = pb.x + 0.5f * pb.z;
        q.w = pb.y + 0.5f * pb.w;
        sq[tid] = q;
    }
    __syncthreads();

    const int k0 = ng * NPW;

    if (tc < 2) {
        // ---- dual path: both targets always valid (max index 255) ----
        const int t1 = tc * 128 + tl;
        const int t2 = t1 + 64;
        float ax0, ay0, ax1, ay1, aw, ah, aa;
        float bx0, by0, bx1, by1, bw, bh, ba;
        load_target(tgt, b * TT + t1, ax0, ay0, ax1, ay1, aw, ah, aa);
        load_target(tgt, b * TT + t2, bx0, by0, bx1, by1, bw, bh, ba);

        float best1 = -INFINITY, sec1 = -INFINITY;
        float best2 = -INFINITY, sec2 = -INFINITY;
        int   i1 = 0, i2 = 0;
        #pragma unroll 3
        for (int k = 0; k < NPW; ++k) {
            const float4 q = sq[k0 + k];  // wave-uniform -> LDS broadcast
            const float pw = q.z - q.x;   // derived, bit-identical to R8
            const float ph = q.w - q.y;
            const float pa = pw * ph;
            giou_step(q, pa, pw, ph, ax0, ay0, ax1, ay1, aw, ah, aa, k,
                      best1, sec1, i1);
            giou_step(q, pa, pw, ph, bx0, by0, bx1, by1, bw, bh, ba, k,
                      best2, sec2, i2);
        }
        int bi1 = k0 + i1, bi2 = k0 + i2;

        rb1[tid] = best1; rs1[tid] = sec1; ri1[tid] = bi1;
        rb2[tid] = best2; rs2[tid] = sec2; ri2[tid] = bi2;
        __syncthreads();

        if (ng == 0) {
            for (int s = 1; s < 4; ++s) { // ascending wave = ascending n
                const float ob1 = rb1[s * 64 + tl];
                const float os1 = rs1[s * 64 + tl];
                const int   oi1 = ri1[s * 64 + tl];
                sec1 = fmaxf(fminf(best1, ob1), fmaxf(sec1, os1));
                if (ob1 > best1) { best1 = ob1; bi1 = oi1; }
                const float ob2 = rb2[s * 64 + tl];
                const float os2 = rs2[s * 64 + tl];
                const int   oi2 = ri2[s * 64 + tl];
                sec2 = fmaxf(fminf(best2, ob2), fmaxf(sec2, os2));
                if (ob2 > best2) { best2 = ob2; bi2 = oi2; }
            }
            const int bt1 = b * TT + t1;
            const int bt2 = b * TT + t2;
            pbest[ns * BB * TT + bt1] = best1;
            psec [ns * BB * TT + bt1] = sec1;
            pidx [ns * BB * TT + bt1] = ns * NPB + bi1;
            pbest[ns * BB * TT + bt2] = best2;
            psec [ns * BB * TT + bt2] = sec2;
            pidx [ns * BB * TT + bt2] = ns * NPB + bi2;
        }
    } else {
        // ---- single path: remainder targets 256..299 ----
        const int t = 256 + tl;
        float ax0 = 0.f, ay0 = 0.f, ax1 = 0.f, ay1 = 0.f;
        float aw = 0.f, ah = 0.f, aa = 0.f;
        if (t < TT)
            load_target(tgt, b * TT + t, ax0, ay0, ax1, ay1, aw, ah, aa);

        float best = -INFINITY, second = -INFINITY;
        int   bidxl = 0;
        #pragma unroll 9
        for (int k = 0; k < NPW; ++k) {
            const float4 q = sq[k0 + k];
            const float pw = q.z - q.x;
            const float ph = q.w - q.y;
            const float pa = pw * ph;
            giou_step(q, pa, pw, ph, ax0, ay0, ax1, ay1, aw, ah, aa, k,
                      best, second, bidxl);
        }
        int bidx = k0 + bidxl;

        rb1[tid] = best; rs1[tid] = second; ri1[tid] = bidx;
        __syncthreads();

        if (ng == 0 && t < TT) {
            for (int s = 1; s < 4; ++s) { // ascending wave = ascending n
                const float ob = rb1[s * 64 + tl];
                const float os = rs1[s * 64 + tl];
                const int   oi = ri1[s * 64 + tl];
                second = fmaxf(fminf(best, ob), fmaxf(second, os));
                if (ob > best) { best = ob; bidx = oi; }
            }
            const int bt = b * TT + t;
            pbest[ns * BB * TT + bt] = best;
            psec [ns * BB * TT + bt] = second;
            pidx [ns * BB * TT + bt] = ns * NPB + bidx;
        }
    }
}

__global__ __launch_bounds__(256) void matcher_finish_kernel(
    const float* __restrict__ pbest,
    const float* __restrict__ psec,
    const int*   __restrict__ pidx,
    const float* __restrict__ pred,
    const float* __restrict__ tgt,
    const unsigned char* __restrict__ mask,
    float* __restrict__ out)
{
    __shared__ int sflag[256];
    __shared__ int scount;

    const int tid = threadIdx.x;
    const int bt  = blockIdx.x * 256 + tid;   // grid covers exactly B*T
    if (tid == 0) scount = 0;
    __syncthreads();

    float best = -INFINITY, second = -INFINITY;
    int   bidx = 0;
    #pragma unroll
    for (int s = 0; s < NSPLIT; ++s) {        // ascending ns = ascending n
        const float ob = pbest[s * BB * TT + bt];
        const float os = psec [s * BB * TT + bt];
        const int   oi = pidx [s * BB * TT + bt];
        second = fmaxf(fminf(best, ob), fmaxf(second, os));
        if (ob > best) { best = ob; bidx = oi; }
    }

    if (best - second > MARGIN) {
        // approx argmax provably exact; recompute winner's GIoU bit-exactly
        const int b = bt / TT;
        const float4 pb = ((const float4*)pred)[b * NN + bidx];
        const float4 tb = ((const float4*)tgt)[bt];
        const float g = giou_exact(pb, tb);
        const bool valid = (mask[bt] != 0) && (g >= 0.5f);
        out[bt]               = (float)bidx;
        out[BB * TT + bt]     = valid ? 1.f : 0.f;
        out[2 * BB * TT + bt] = g;
    } else {
        const int pos = atomicAdd(&scount, 1);
        sflag[pos] = tid;
    }
    __syncthreads();

    // cooperative exact rescan of ambiguous targets: one wave per entry
    const int cnt  = scount;
    const int lane = tid & 63;
    const int ng   = tid >> 6;
    for (int f = ng; f < cnt; f += 4) {
        const int fbt = blockIdx.x * 256 + sflag[f];
        const int b   = fbt / TT;
        const float4 tb = ((const float4*)tgt)[fbt];

        float bestx = -INFINITY;
        int   bix   = NN;
        for (int n = lane; n < NN; n += 64) {   // ascending n per lane
            const float4 pb = ((const float4*)pred)[b * NN + n];
            const float g = giou_exact(pb, tb);
            if (g > bestx) { bestx = g; bix = n; }
        }
        // cross-lane reduce: max g, lowest n on bit-ties (numpy first-occ.)
        for (int off = 32; off >= 1; off >>= 1) {
            const float ob = __shfl_xor(bestx, off);
            const int   oi = __shfl_xor(bix, off);
            if (ob > bestx || (ob == bestx && oi < bix)) { bestx = ob; bix = oi; }
        }
        if (lane == 0) {
            const bool valid = (mask[fbt] != 0) && (bestx >= 0.5f);
            out[fbt]               = (float)bix;
            out[BB * TT + fbt]     = valid ? 1.f : 0.f;
            out[2 * BB * TT + fbt] = bestx;
        }
    }
}

extern "C" void kernel_launch(void* const* d_in, const int* in_sizes, int n_in,
                              void* d_out, int out_size, void* d_ws, size_t ws_size,
                              hipStream_t stream) {
    const float* pred = (const float*)d_in[0];
    const float* tgt  = (const float*)d_in[1];
    const unsigned char* mask = (const unsigned char*)d_in[2];
    float* out = (float*)d_out;

    const size_t seg = (size_t)NSPLIT * BB * TT * 4;   // 768 KB per array
    char* ws = (char*)d_ws;
    float* pbest = (float*)ws;
    float* psec  = (float*)(ws + seg);
    int*   pidx  = (int*)  (ws + 2 * seg);             // total ~2.3 MB

    matcher_scan_kernel<<<dim3(BB * 3 * NSPLIT), dim3(256), 0, stream>>>(
        (const float4*)pred, (const float4*)tgt, pbest, psec, pidx);
    matcher_finish_kernel<<<dim3(BB * TT / 256), dim3(256), 0, stream>>>(
        pbest, psec, pidx, pred, tgt, mask, out);
}